// Round 1
// baseline (521.969 us; speedup 1.0000x reference)
//
#include <hip/hip_runtime.h>
#include <hip/hip_bf16.h>

#define DEV __device__ __forceinline__

typedef __bf16 bf16x8 __attribute__((ext_vector_type(8)));
typedef float f32x4 __attribute__((ext_vector_type(4)));

DEV f32x4 mfma16(bf16x8 a, bf16x8 b, f32x4 c) {
  return __builtin_amdgcn_mfma_f32_16x16x32_bf16(a, b, c, 0, 0, 0);
}

DEV ushort f2bf(float f) {
  union { __hip_bfloat16 h; ushort u; } cv;
  cv.h = __float2bfloat16(f);
  return cv.u;
}
DEV float bf2f(ushort u) {
  union { float f; unsigned v; } cv; cv.v = ((unsigned)u) << 16; return cv.f;
}

// ---------------- constants ----------------
// B=4 H=8 S=2048 D=256; BH=32; M=B*S=8192; Nqkv=3*H*D=6144; F=H*D=2048

// ---------------- kernel A: fp32 -> bf16 conversion ----------------
// dst layout (ushort elems): xb @0 (2^21), wq @2097152, wk @2621440, wv @3145728, wo @3670016
__global__ __launch_bounds__(256) void convert_all(
    const float* __restrict__ x, const float* __restrict__ wq,
    const float* __restrict__ wk, const float* __restrict__ wv,
    const float* __restrict__ wo, ushort* __restrict__ dst)
{
  size_t i = ((size_t)blockIdx.x * 256 + threadIdx.x) * 4;
  const float* src; size_t off;
  if (i < (size_t)2097152) { src = x; off = i; }
  else {
    size_t j = i - 2097152;
    unsigned wsel = (unsigned)(j >> 19);
    off = j & 524287;
    src = wsel == 0 ? wq : wsel == 1 ? wk : wsel == 2 ? wv : wo;
  }
  float4 v = *(const float4*)(src + off);
  ushort4 o;
  o.x = f2bf(v.x); o.y = f2bf(v.y); o.z = f2bf(v.z); o.w = f2bf(v.w);
  *(ushort4*)(dst + i) = o;
}

// ---------------- GEMM template (NT: A[M,K] row-major, Bt[N,K] row-major) ----------------
// EPI 0: fused QKV projection epilogue (N=6144 = [Q|K|V] each 2048 wide, bias fp32, Q scaled 1/16,
//        scattered bf16 stores to [BH, S, D] layout)
// EPI 1: out = acc + bo, fp32 store to d_out [M, 256]
template<int BM, int BN, int EPI>
__global__ __launch_bounds__(256, 2) void gemm_nt(
    const ushort* __restrict__ A,
    const ushort* __restrict__ W0, const ushort* __restrict__ W1, const ushort* __restrict__ W2,
    int K,
    const float* __restrict__ b0, const float* __restrict__ b1, const float* __restrict__ b2,
    ushort* __restrict__ Qo, ushort* __restrict__ Ko, ushort* __restrict__ Vo,
    float* __restrict__ fo)
{
  constexpr int WM = BM / 2, WN = BN / 2, MF = WM / 16, NF = WN / 16;
  constexpr int CA = BM / 64, CB = BN / 64; // 16B chunks per thread per tile
  const int n0 = blockIdx.x * BN, m0 = blockIdx.y * BM;
  const int tid = threadIdx.x, lane = tid & 63;
  const int wm = (tid >> 7) & 1, wn = (tid >> 6) & 1;

  __shared__ ushort As[BM * 40]; // rows padded to 40 ushorts (80B): ~2-way bank conflicts
  __shared__ ushort Bs[BN * 40];

  const ushort* Bt;
  if (EPI == 0) {
    int p = n0 >> 11;
    Bt = (p == 0 ? W0 : p == 1 ? W1 : W2) + (size_t)(n0 & 2047) * K;
  } else {
    Bt = W0 + (size_t)n0 * K;
  }

  f32x4 acc[MF][NF];
#pragma unroll
  for (int m = 0; m < MF; m++)
#pragma unroll
    for (int n = 0; n < NF; n++) acc[m][n] = (f32x4){0.f, 0.f, 0.f, 0.f};

  for (int k0 = 0; k0 < K; k0 += 32) {
#pragma unroll
    for (int i = 0; i < CA; i++) {
      int ci = tid * CA + i; int r = ci >> 2, c = ci & 3;
      *(uint4*)&As[r * 40 + c * 8] = *(const uint4*)&A[(size_t)(m0 + r) * K + k0 + c * 8];
    }
#pragma unroll
    for (int i = 0; i < CB; i++) {
      int ci = tid * CB + i; int r = ci >> 2, c = ci & 3;
      *(uint4*)&Bs[r * 40 + c * 8] = *(const uint4*)&Bt[(size_t)r * K + k0 + c * 8];
    }
    __syncthreads();
    bf16x8 af[MF], bfr[NF];
#pragma unroll
    for (int m = 0; m < MF; m++)
      af[m] = *(const bf16x8*)&As[(wm * WM + m * 16 + (lane & 15)) * 40 + ((lane >> 4) << 3)];
#pragma unroll
    for (int n = 0; n < NF; n++)
      bfr[n] = *(const bf16x8*)&Bs[(wn * WN + n * 16 + (lane & 15)) * 40 + ((lane >> 4) << 3)];
#pragma unroll
    for (int m = 0; m < MF; m++)
#pragma unroll
      for (int n = 0; n < NF; n++) acc[m][n] = mfma16(af[m], bfr[n], acc[m][n]);
    __syncthreads();
  }

  if (EPI == 0) {
    const int p = n0 >> 11;
    const float* bias = (p == 0 ? b0 : p == 1 ? b1 : b2);
    ushort* dst = (p == 0 ? Qo : p == 1 ? Ko : Vo);
    const float scl = (p == 0 ? 0.0625f : 1.0f); // fold 1/sqrt(D) into Q
#pragma unroll
    for (int m = 0; m < MF; m++)
#pragma unroll
      for (int n = 0; n < NF; n++)
#pragma unroll
        for (int r = 0; r < 4; r++) {
          int row = m0 + wm * WM + m * 16 + ((lane >> 4) << 2) + r;
          int col = n0 + wn * WN + n * 16 + (lane & 15);
          int ce = col & 2047;
          float v = (acc[m][n][r] + bias[ce]) * scl;
          int b = row >> 11, s = row & 2047, h = ce >> 8, e = ce & 255;
          dst[((size_t)((b * 8 + h) * 2048 + s) << 8) + e] = f2bf(v);
        }
  } else {
#pragma unroll
    for (int m = 0; m < MF; m++)
#pragma unroll
      for (int n = 0; n < NF; n++)
#pragma unroll
        for (int r = 0; r < 4; r++) {
          int row = m0 + wm * WM + m * 16 + ((lane >> 4) << 2) + r;
          int col = n0 + wn * WN + n * 16 + (lane & 15);
          fo[(size_t)row * 256 + col] = acc[m][n][r] + b0[col];
        }
  }
}

// ---------------- attention core ----------------
// grid (32 s-tiles, 32 bh); block 256 = 4 waves; s-tile = 64 rows (wave w owns rows w*16..w*16+15 for QK^T)
// PHASE 0: column sums of exp(G) -> lpart[stile][bh][t]  (deterministic partials, no atomics)
// PHASE 1: Z[s, h*256+e] = sum_t exp(G[s,t]) * Vt_scaled[e,t]
template<int PHASE>
__global__ __launch_bounds__(256, 2) void attn_core(
    const ushort* __restrict__ Qb, const ushort* __restrict__ Kb,
    const ushort* __restrict__ Vt, float* __restrict__ lpart,
    ushort* __restrict__ Zb)
{
  const int stile = blockIdx.x, bh = blockIdx.y;
  const int s0 = stile * 64;
  const int tid = threadIdx.x, lane = tid & 63, w = tid >> 6;

  __shared__ ushort Ks[32 * 264];                       // 32 t-rows, 512B data + 16B pad
  __shared__ __align__(16) char xbuf[PHASE == 0 ? 32768 : 25600];
  float* colsum = (float*)xbuf;                         // PHASE0: [4][2048]
  ushort* Vs = (ushort*)xbuf;                           // PHASE1: [256 e][40] (32 t + pad)
  ushort* Ps = (ushort*)(xbuf + 20480);                 // PHASE1: [64 s][40]

  // Q fragments for this wave's 16 rows, full K=256 (8 k-steps)
  bf16x8 q[8];
  {
    const ushort* qrow = &Qb[((size_t)bh * 2048 + s0 + w * 16 + (lane & 15)) * 256 + ((lane >> 4) << 3)];
#pragma unroll
    for (int kk = 0; kk < 8; kk++) q[kk] = *(const bf16x8*)&qrow[kk * 32];
  }

  f32x4 acc[4][4];
  if (PHASE == 1) {
#pragma unroll
    for (int m = 0; m < 4; m++)
#pragma unroll
      for (int n = 0; n < 4; n++) acc[m][n] = (f32x4){0.f, 0.f, 0.f, 0.f};
  }

  for (int t0 = 0; t0 < 2048; t0 += 32) {
    { // stage K tile [32][256]
      int r = tid >> 3; int cb = (tid & 7) * 32;
      const ushort* kg = &Kb[((size_t)bh * 2048 + t0 + r) * 256 + cb];
      ushort* ks = &Ks[r * 264 + cb];
#pragma unroll
      for (int i = 0; i < 4; i++) *(uint4*)&ks[i * 8] = *(const uint4*)&kg[i * 8];
    }
    if constexpr (PHASE == 1) { // stage V^T tile [256 e][32 t]
      const ushort* vg = &Vt[((size_t)bh * 256 + tid) * 2048 + t0];
      ushort* vs = &Vs[tid * 40];
#pragma unroll
      for (int i = 0; i < 4; i++) *(uint4*)&vs[i * 8] = *(const uint4*)&vg[i * 8];
    }
    __syncthreads();

    // G1: G[s(16), t(32)] for this wave
    f32x4 g[2];
    g[0] = (f32x4){0.f, 0.f, 0.f, 0.f};
    g[1] = (f32x4){0.f, 0.f, 0.f, 0.f};
#pragma unroll
    for (int n = 0; n < 2; n++)
#pragma unroll
      for (int kk = 0; kk < 8; kk++) {
        bf16x8 kb = *(const bf16x8*)&Ks[(n * 16 + (lane & 15)) * 264 + kk * 32 + ((lane >> 4) << 3)];
        g[n] = mfma16(q[kk], kb, g[n]);
      }

    if constexpr (PHASE == 0) {
#pragma unroll
      for (int n = 0; n < 2; n++) {
        float sn = __expf(g[n][0]) + __expf(g[n][1]) + __expf(g[n][2]) + __expf(g[n][3]);
        sn += __shfl_xor(sn, 16);
        sn += __shfl_xor(sn, 32);
        if ((lane >> 4) == 0) colsum[w * 2048 + t0 + n * 16 + lane] = sn;
      }
      __syncthreads();
    } else {
      // P = exp(G) -> LDS (bf16)
#pragma unroll
      for (int n = 0; n < 2; n++)
#pragma unroll
        for (int r = 0; r < 4; r++)
          Ps[(w * 16 + ((lane >> 4) << 2) + r) * 40 + n * 16 + (lane & 15)] = f2bf(__expf(g[n][r]));
      __syncthreads();
      // G2: Z[s(64), e(64 for this wave)] += P[64,32] * V'[32, e]
      bf16x8 pa[4];
#pragma unroll
      for (int m = 0; m < 4; m++)
        pa[m] = *(const bf16x8*)&Ps[(m * 16 + (lane & 15)) * 40 + ((lane >> 4) << 3)];
#pragma unroll
      for (int n = 0; n < 4; n++) {
        bf16x8 vb = *(const bf16x8*)&Vs[(w * 64 + n * 16 + (lane & 15)) * 40 + ((lane >> 4) << 3)];
#pragma unroll
        for (int m = 0; m < 4; m++) acc[m][n] = mfma16(pa[m], vb, acc[m][n]);
      }
      __syncthreads();
    }
  }

  if constexpr (PHASE == 0) {
    for (int c = tid; c < 2048; c += 256) {
      float t = colsum[c] + colsum[2048 + c] + colsum[4096 + c] + colsum[6144 + c];
      lpart[((size_t)stile * 32 + bh) * 2048 + c] = t;
    }
  } else {
    const int b = bh >> 3, h = bh & 7;
#pragma unroll
    for (int m = 0; m < 4; m++)
#pragma unroll
      for (int n = 0; n < 4; n++)
#pragma unroll
        for (int r = 0; r < 4; r++) {
          int sl = m * 16 + ((lane >> 4) << 2) + r;
          int el = w * 64 + n * 16 + (lane & 15);
          Zb[((size_t)(b * 2048 + s0 + sl)) * 2048 + h * 256 + el] = f2bf(acc[m][n][r]);
        }
  }
}

// ---------------- V transpose + scale by 1/l_t ----------------
// grid (32 t-tiles, 32 bh); V[bh, t, e] -> Vt[bh, e, t] * (1/l_t)
__global__ __launch_bounds__(256) void vscale_t(
    const ushort* __restrict__ V, const float* __restrict__ lpart,
    ushort* __restrict__ Vt)
{
  const int t0 = blockIdx.x * 64, bh = blockIdx.y, tid = threadIdx.x;
  __shared__ float cinv[64];
  __shared__ ushort Tt[64 * 72];
  if (tid < 64) {
    float s = 0.f;
    for (int st = 0; st < 32; ++st) s += lpart[((size_t)st * 32 + bh) * 2048 + t0 + tid];
    cinv[tid] = 1.0f / s;
  }
  __syncthreads();
  const int tr = tid >> 2, cc = tid & 3;
  for (int et = 0; et < 4; ++et) {
    int e0 = et * 64;
    const ushort* src = &V[((size_t)bh * 2048 + t0 + tr) * 256 + e0 + cc * 16];
    *(uint4*)&Tt[tr * 72 + cc * 16] = *(const uint4*)&src[0];
    *(uint4*)&Tt[tr * 72 + cc * 16 + 8] = *(const uint4*)&src[8];
    __syncthreads();
    ushort outv[16];
    const int e = tid >> 2;
#pragma unroll
    for (int j = 0; j < 16; j++) {
      int s = cc * 16 + j;
      outv[j] = f2bf(bf2f(Tt[s * 72 + e]) * cinv[s]);
    }
    ushort* dst = &Vt[((size_t)bh * 256 + e0 + e) * 2048 + t0 + cc * 16];
    *(uint4*)&dst[0] = *(const uint4*)&outv[0];
    *(uint4*)&dst[8] = *(const uint4*)&outv[8];
    __syncthreads();
  }
}

// ---------------- launch ----------------
extern "C" void kernel_launch(void* const* d_in, const int* in_sizes, int n_in,
                              void* d_out, int out_size, void* d_ws, size_t ws_size,
                              hipStream_t stream) {
  const float* x  = (const float*)d_in[0];
  const float* Wq = (const float*)d_in[1];
  const float* bq = (const float*)d_in[2];
  const float* Wk = (const float*)d_in[3];
  const float* bk = (const float*)d_in[4];
  const float* Wv = (const float*)d_in[5];
  const float* bv = (const float*)d_in[6];
  const float* Wo = (const float*)d_in[7];
  const float* bo = (const float*)d_in[8];

  if (ws_size < (size_t)184549376) return; // need 176 MB scratch; fail loud (poisoned out)

  char* ws = (char*)d_ws;
  ushort* bfb = (ushort*)ws;                       // converted bf16 region (8 MB)
  ushort* xb  = bfb;
  ushort* wqb = bfb + 2097152;
  ushort* wkb = bfb + 2621440;
  ushort* wvb = bfb + 3145728;
  ushort* wob = bfb + 3670016;
  ushort* Qb = (ushort*)(ws + 8388608);            // [32, 2048, 256] bf16, 32 MB (pre-scaled 1/16)
  ushort* Kb = (ushort*)(ws + 41943040);           // 32 MB
  ushort* Vb = (ushort*)(ws + 75497472);           // 32 MB
  ushort* Vt = (ushort*)(ws + 109051904);          // [32, 256, 2048] scaled, 32 MB
  ushort* Zb = (ushort*)(ws + 142606336);          // [8192, 2048] bf16, 32 MB
  float*  lp = (float*)(ws + 176160768);           // [32 stiles, 32 bh, 2048] fp32, 8 MB
  float* out = (float*)d_out;

  convert_all<<<4096, 256, 0, stream>>>(x, Wq, Wk, Wv, Wo, bfb);
  gemm_nt<128, 128, 0><<<dim3(48, 64), 256, 0, stream>>>(
      xb, wqb, wkb, wvb, 256, bq, bk, bv, Qb, Kb, Vb, nullptr);
  attn_core<0><<<dim3(32, 32), 256, 0, stream>>>(Qb, Kb, nullptr, lp, nullptr);
  vscale_t<<<dim3(32, 32), 256, 0, stream>>>(Vb, lp, Vt);
  attn_core<1><<<dim3(32, 32), 256, 0, stream>>>(Qb, Kb, Vt, lp, Zb);
  gemm_nt<128, 64, 1><<<dim3(4, 64), 256, 0, stream>>>(
      Zb, wob, wob, wob, 2048, bo, bo, bo, nullptr, nullptr, nullptr, out);
}